// Round 7
// baseline (437.146 us; speedup 1.0000x reference)
//
#include <hip/hip_runtime.h>
#include <cstdint>
#include <cstddef>

#define CHUNK 4096

typedef __attribute__((ext_vector_type(8))) short short8;
typedef __attribute__((ext_vector_type(4))) float f32x4;

__device__ __forceinline__ float bf2f(unsigned short u) {
  return __uint_as_float(((unsigned)u) << 16);
}
__device__ __forceinline__ unsigned short f2bf(float f) {
  unsigned u = __float_as_uint(f);
  u += 0x7fffu + ((u >> 16) & 1u);   // RNE
  return (unsigned short)(u >> 16);
}

// both W1,W2 [128][128] fp32 -> Wt[n][k] bf16, single launch (grid 128)
__global__ void transpose2_w_k(const float* __restrict__ W1, const float* __restrict__ W2,
                               unsigned short* __restrict__ W1t, unsigned short* __restrict__ W2t) {
  int idx = blockIdx.x * 256 + threadIdx.x;
  const float* W = (idx < 16384) ? W1 : W2;
  unsigned short* Wt = (idx < 16384) ? W1t : W2t;
  int i = idx & 16383;
  int k = i >> 7, n = i & 127;
  Wt[n * 128 + k] = f2bf(W[i]);
}

// ---------------- fallback CSR build (N > 65535) ----------------
__global__ void count_edges_k(const int* __restrict__ dst, int E, int* __restrict__ cnt) {
  int e = blockIdx.x * blockDim.x + threadIdx.x;
  if (e < E) atomicAdd(&cnt[dst[e]], 1);
}

__global__ void dinv_k(const int* __restrict__ cnt, float* __restrict__ dinv, int n) {
  int i = blockIdx.x * blockDim.x + threadIdx.x;
  if (i < n) dinv[i] = rsqrtf((float)cnt[i] + 1.0f);
}

template <typename CT>
__global__ void fill_csr_k(const int* __restrict__ src, const int* __restrict__ dst, int E,
                           int* __restrict__ cursor, CT* __restrict__ col) {
  int e = blockIdx.x * blockDim.x + threadIdx.x;
  if (e < E) {
    int d = dst[e], s = src[e];
    int pos = atomicAdd(&cursor[d], 1);
    col[pos] = (CT)s;
  }
}

__global__ void scan1_k(const int* __restrict__ cnt, int* __restrict__ rs,
                        int* __restrict__ partials, int n) {
  __shared__ int s[1024];
  int t = threadIdx.x;
  int gid = blockIdx.x * 1024 + t;
  int v = (gid < n) ? cnt[gid] : 0;
  s[t] = v;
  __syncthreads();
  for (int off = 1; off < 1024; off <<= 1) {
    int u = (t >= off) ? s[t - off] : 0;
    __syncthreads();
    s[t] += u;
    __syncthreads();
  }
  if (gid < n) rs[gid] = s[t] - v;
  if (t == 1023) partials[blockIdx.x] = s[1023];
}

__global__ void scan2_k(int* __restrict__ partials, int nb) {
  if (threadIdx.x == 0 && blockIdx.x == 0) {
    int acc = 0;
    for (int i = 0; i < nb; i++) { int v = partials[i]; partials[i] = acc; acc += v; }
  }
}

__global__ void scan3_k(int* __restrict__ rs, int* __restrict__ cursor,
                        const int* __restrict__ partials, int n, int total) {
  int gid = blockIdx.x * blockDim.x + threadIdx.x;
  if (gid < n) {
    int v = rs[gid] + partials[gid >> 10];
    rs[gid] = v;
    cursor[gid] = v;
  }
  if (gid == 0) rs[n] = total;
}

// ---------------- two-level bucket CSR build (N <= 65535) ----------------
__global__ __launch_bounds__(256) void hist_k(const int* __restrict__ dst, int E,
                                              int* __restrict__ blk_cnt, int nblk, int B) {
  __shared__ int h[256];
  int t = threadIdx.x;
  if (t < B) h[t] = 0;
  __syncthreads();
  int e0 = blockIdx.x * CHUNK;
  int e1 = e0 + CHUNK; if (e1 > E) e1 = E;
  for (int e = e0 + t; e < e1; e += 256) atomicAdd(&h[dst[e] >> 8], 1);
  __syncthreads();
  if (t < B) blk_cnt[(size_t)t * nblk + blockIdx.x] = h[t];
}

__global__ __launch_bounds__(256) void bucket_prefix_k(int* __restrict__ blk_cnt, int nblk, int B,
                                                       int* __restrict__ bucket_tot) {
  int wid = (blockIdx.x * 256 + threadIdx.x) >> 6;
  int lane = threadIdx.x & 63;
  if (wid >= B) return;
  int* p = blk_cnt + (size_t)wid * nblk;
  int running = 0;
  for (int c0 = 0; c0 < nblk; c0 += 64) {
    int idx = c0 + lane;
    int orig = (idx < nblk) ? p[idx] : 0;
    int v = orig;
    #pragma unroll
    for (int off = 1; off < 64; off <<= 1) {
      int u = __shfl_up(v, off);
      if (lane >= off) v += u;
    }
    int tot = __shfl(v, 63);
    if (idx < nblk) p[idx] = running + (v - orig);
    running += tot;
  }
  if (lane == 0) bucket_tot[wid] = running;
}

__global__ void bucket_base_k(const int* __restrict__ bucket_tot, int B,
                              int* __restrict__ bucket_base) {
  int lane = threadIdx.x;
  int running = 0;
  for (int c0 = 0; c0 < B; c0 += 64) {
    int idx = c0 + lane;
    int orig = (idx < B) ? bucket_tot[idx] : 0;
    int v = orig;
    #pragma unroll
    for (int off = 1; off < 64; off <<= 1) {
      int u = __shfl_up(v, off);
      if (lane >= off) v += u;
    }
    int tot = __shfl(v, 63);
    if (idx < B) bucket_base[idx] = running + (v - orig);
    running += tot;
  }
  if (lane == 0) bucket_base[B] = running;
}

__global__ __launch_bounds__(256) void bucket_scatter_k(const int* __restrict__ src,
                                                        const int* __restrict__ dst, int E,
                                                        const int* __restrict__ blk_pre, int nblk,
                                                        const int* __restrict__ bucket_base, int B,
                                                        unsigned int* __restrict__ tmp) {
  __shared__ int h[256];
  __shared__ int base_s[256];
  int t = threadIdx.x;
  if (t < B) {
    h[t] = 0;
    base_s[t] = bucket_base[t] + blk_pre[(size_t)t * nblk + blockIdx.x];
  }
  __syncthreads();
  int e0 = blockIdx.x * CHUNK;
  int e1 = e0 + CHUNK; if (e1 > E) e1 = E;
  for (int e = e0 + t; e < e1; e += 256) {
    int d = dst[e];
    int b = d >> 8;
    int r = atomicAdd(&h[b], 1);
    tmp[base_s[b] + r] = ((unsigned)src[e] << 8) | (unsigned)(d & 255);
  }
}

__global__ __launch_bounds__(256) void bucket_cntfill_k(const unsigned int* __restrict__ tmp,
                                                        const int* __restrict__ bucket_base,
                                                        int N, int E,
                                                        float* __restrict__ dinv,
                                                        int* __restrict__ rs,
                                                        unsigned short* __restrict__ col) {
  __shared__ int c[256];
  __shared__ int cur[256];
  int b = blockIdx.x, t = threadIdx.x;
  c[t] = 0;
  __syncthreads();
  int s0 = bucket_base[b], s1 = bucket_base[b + 1];
  for (int i = s0 + t; i < s1; i += 256) atomicAdd(&c[tmp[i] & 255u], 1);
  __syncthreads();
  int v = c[t];
  cur[t] = v;
  __syncthreads();
  for (int off = 1; off < 256; off <<= 1) {
    int u = (t >= off) ? cur[t - off] : 0;
    __syncthreads();
    cur[t] += u;
    __syncthreads();
  }
  int rsv = s0 + cur[t] - v;
  int node = (b << 8) + t;
  if (node < N) {
    rs[node] = rsv;
    dinv[node] = rsqrtf((float)v + 1.0f);
  }
  if (b == 0 && t == 0) rs[N] = E;
  __syncthreads();
  cur[t] = rsv;
  __syncthreads();
  for (int i = s0 + t; i < s1; i += 256) {
    unsigned u = tmp[i];
    int pos = atomicAdd(&cur[u & 255u], 1);
    col[pos] = (unsigned short)(u >> 8);
  }
}

// ---------------- MFMA GEMM: chunk-major I/O ----------------
// Output C is chunk-major: C[(c*N + r)*32 + f], c = f_global>>5.
// A: AF32 -> fp32 row-major (x input); else bf16 chunk-major (chunk == ks).
template <bool AF32>
__global__ __launch_bounds__(256) void gemm_bf_k(const void* __restrict__ Ap,
                                                 const unsigned short* __restrict__ Wt,
                                                 unsigned short* __restrict__ C, int N) {
  __shared__ unsigned short Ws[128 * 136];   // 34.8KB; reused as Cs (128*132=33.8KB)
  for (int idx = threadIdx.x; idx < 2048; idx += 256) {
    int n = idx >> 4, c = idx & 15;
    *(uint4*)&Ws[n * 136 + c * 8] = ((const uint4*)Wt)[idx];
  }
  __syncthreads();
  const int w = threadIdx.x >> 6;
  const int lane = threadIdx.x & 63;
  const int quad = lane >> 4, l16 = lane & 15;
  const int rb = blockIdx.x * 128 + w * 32;
  f32x4 acc[2][8] = {};
  #pragma unroll
  for (int ks = 0; ks < 4; ks++) {
    short8 aF[2];
    #pragma unroll
    for (int m = 0; m < 2; m++) {
      int r = rb + m * 16 + l16;
      short8 a = {};
      if (r < N) {
        if (AF32) {
          const float* ar = (const float*)Ap + (size_t)r * 128 + ks * 32 + quad * 8;
          float4 u0 = *(const float4*)ar;
          float4 u1 = *(const float4*)(ar + 4);
          a[0] = (short)f2bf(u0.x); a[1] = (short)f2bf(u0.y);
          a[2] = (short)f2bf(u0.z); a[3] = (short)f2bf(u0.w);
          a[4] = (short)f2bf(u1.x); a[5] = (short)f2bf(u1.y);
          a[6] = (short)f2bf(u1.z); a[7] = (short)f2bf(u1.w);
        } else {
          // chunk-major: chunk == ks
          a = *(const short8*)((const unsigned short*)Ap + ((size_t)ks * N + r) * 32 + quad * 8);
        }
      }
      aF[m] = a;
    }
    #pragma unroll
    for (int t = 0; t < 8; t++) {
      short8 bF = *(const short8*)&Ws[(t * 16 + l16) * 136 + ks * 32 + quad * 8];
      acc[0][t] = __builtin_amdgcn_mfma_f32_16x16x32_bf16(aF[0], bF, acc[0][t], 0, 0, 0);
      acc[1][t] = __builtin_amdgcn_mfma_f32_16x16x32_bf16(aF[1], bF, acc[1][t], 0, 0, 0);
    }
  }
  __syncthreads();
  unsigned short* Cs = Ws;
  #pragma unroll
  for (int m = 0; m < 2; m++) {
    int rloc = w * 32 + m * 16 + quad * 4;
    #pragma unroll
    for (int t = 0; t < 8; t++)
      #pragma unroll
      for (int rg = 0; rg < 4; rg++)
        Cs[(rloc + rg) * 132 + t * 16 + l16] = f2bf(acc[m][t][rg]);
  }
  __syncthreads();
  const int r0 = blockIdx.x * 128;
  for (int idx = threadIdx.x; idx < 2048; idx += 256) {
    int row = idx >> 4, seg = idx & 15;          // seg: 8-feature segment
    int rr = r0 + row;
    if (rr < N) {
      uint2 a = *(uint2*)&Cs[row * 132 + seg * 8];
      uint2 b = *(uint2*)&Cs[row * 132 + seg * 8 + 4];
      int chunk = seg >> 2, sub = seg & 3;
      ((uint4*)C)[((size_t)chunk * N + rr) * 4 + sub] = make_uint4(a.x, a.y, b.x, b.y);
    }
  }
}

// ---------------- aggregation: XCD-pinned feature chunks ----------------
// h chunk-major [4][N][32] bf16. slot = blockIdx&7 (round-robin -> XCD),
// chunk = slot>>1, half = slot&1. Wave = 1 node; 16 lanes/edge (dword = 2 feats),
// 4 groups x unroll2 = 8 edges in flight.
template <typename CT, bool OUTF32>
__global__ __launch_bounds__(256) void aggc_k(const unsigned short* __restrict__ h,
                                              const int* __restrict__ rs,
                                              const CT* __restrict__ col,
                                              const float* __restrict__ dinv,
                                              const float* __restrict__ bias,
                                              void* __restrict__ outp, int n, int half) {
  const int slot = blockIdx.x & 7;
  const int chunk = slot >> 1;
  const int hh = slot & 1;
  const int node = hh * half + ((blockIdx.x >> 3) << 2) + (threadIdx.x >> 6);
  const int hiB = hh ? n : half;
  if (node >= hiB) return;
  const int lane = threadIdx.x & 63;
  const int g = lane >> 4, l = lane & 15;
  const unsigned* hc = (const unsigned*)h + (size_t)chunk * n * 16;
  float di = dinv[node];
  unsigned sv = hc[(size_t)node * 16 + l];
  float ws = (g == 0) ? di : 0.f;
  float a0 = bf2f((unsigned short)sv) * ws;
  float a1 = bf2f((unsigned short)(sv >> 16)) * ws;
  int beg = rs[node], end = rs[node + 1];
  for (int base = beg; base < end; base += 8) {
    int e0 = base + g, e1 = base + 4 + g;
    int i0 = (e0 < end) ? e0 : end - 1;
    int i1 = (e1 < end) ? e1 : end - 1;
    int s0 = (int)col[i0], s1 = (int)col[i1];
    float w0 = (e0 < end) ? dinv[s0] : 0.f;
    float w1 = (e1 < end) ? dinv[s1] : 0.f;
    unsigned v0 = hc[(size_t)s0 * 16 + l];
    unsigned v1 = hc[(size_t)s1 * 16 + l];
    a0 += bf2f((unsigned short)v0) * w0 + bf2f((unsigned short)v1) * w1;
    a1 += bf2f((unsigned short)(v0 >> 16)) * w0 + bf2f((unsigned short)(v1 >> 16)) * w1;
  }
  a0 += __shfl_xor(a0, 16); a0 += __shfl_xor(a0, 32);
  a1 += __shfl_xor(a1, 16); a1 += __shfl_xor(a1, 32);
  if (g == 0) {
    float b0 = bias[chunk * 32 + l * 2];
    float b1 = bias[chunk * 32 + l * 2 + 1];
    float r0 = fmaxf(a0 * di + b0, 0.f);
    float r1 = fmaxf(a1 * di + b1, 0.f);
    if (OUTF32) {
      // row-major fp32 for pool
      *(float2*)((float*)outp + (size_t)node * 128 + chunk * 32 + l * 2) = make_float2(r0, r1);
    } else {
      // chunk-major bf16 for next gemm
      ((unsigned*)outp)[((size_t)chunk * n + node) * 16 + l] =
          (unsigned)f2bf(r0) | ((unsigned)f2bf(r1) << 16);
    }
  }
}

// ---------------- per-graph mean pool ----------------
__global__ void pool_k(const float* __restrict__ h, const int* __restrict__ batch, int n,
                       float* __restrict__ pool, float* __restrict__ gcnt) {
  int f = threadIdx.x;
  int n0 = blockIdx.x * 64;
  if (n0 >= n) return;
  int n1 = n0 + 64; if (n1 > n) n1 = n;
  int gcur = batch[n0];
  float acc = 0.f, cacc = 0.f;
  for (int i = n0; i < n1; i++) {
    int g = batch[i];
    if (g != gcur) {
      atomicAdd(&pool[gcur * 128 + f], acc);
      if (f == 0) atomicAdd(&gcnt[gcur], cacc);
      acc = 0.f; cacc = 0.f; gcur = g;
    }
    acc += h[(size_t)i * 128 + f];
    cacc += 1.f;
  }
  atomicAdd(&pool[gcur * 128 + f], acc);
  if (f == 0) atomicAdd(&gcnt[gcur], cacc);
}

// ---------------- classifier head ----------------
__global__ void classify_k(const float* __restrict__ pool, const float* __restrict__ gcnt,
                           const float* __restrict__ Wc1, const float* __restrict__ bc1,
                           const float* __restrict__ Wc2, const float* __restrict__ bc2,
                           float* __restrict__ out, int nc) {
  __shared__ float gs[128];
  __shared__ float zs[128];
  int g = blockIdx.x, t = threadIdx.x;
  float c = gcnt[g]; if (c < 1.f) c = 1.f;
  gs[t] = pool[g * 128 + t] / c;
  __syncthreads();
  float acc = bc1[t];
  for (int k = 0; k < 128; k++) acc += gs[k] * Wc1[k * 128 + t];
  zs[t] = fmaxf(acc, 0.f);
  __syncthreads();
  if (t < nc) {
    float o = bc2[t];
    for (int k = 0; k < 128; k++) o += zs[k] * Wc2[k * nc + t];
    out[g * nc + t] = o;
  }
}

extern "C" void kernel_launch(void* const* d_in, const int* in_sizes, int n_in,
                              void* d_out, int out_size, void* d_ws, size_t ws_size,
                              hipStream_t stream) {
  const float* x   = (const float*)d_in[0];
  const int*   ei  = (const int*)d_in[1];
  const int*   bat = (const int*)d_in[2];
  const float* W1  = (const float*)d_in[3];
  const float* b1  = (const float*)d_in[4];
  const float* W2  = (const float*)d_in[5];
  const float* b2  = (const float*)d_in[6];
  const float* Wc1 = (const float*)d_in[7];
  const float* bc1 = (const float*)d_in[8];
  const float* Wc2 = (const float*)d_in[9];
  const float* bc2 = (const float*)d_in[10];
  float* out = (float*)d_out;

  const int N  = in_sizes[0] / 128;
  const int E  = in_sizes[1] / 2;
  const int NC = in_sizes[10];
  const int G  = out_size / NC;
  const int* src = ei;
  const int* dst = ei + E;
  (void)n_in; (void)ws_size;

  size_t off = 0;
  auto walloc = [&](size_t bytes) -> void* {
    void* p = (char*)d_ws + off;
    off += (bytes + 255) & ~(size_t)255;
    return p;
  };
  unsigned short* B2 = (unsigned short*)walloc((size_t)N * 128 * 2);
  unsigned short* B3 = (unsigned short*)walloc((size_t)N * 128 * 2);
  float* a2   = (float*)walloc((size_t)N * 128 * 4);
  unsigned short* W1t = (unsigned short*)walloc(128 * 128 * 2);
  unsigned short* W2t = (unsigned short*)walloc(128 * 128 * 2);
  float* dinv = (float*)walloc((size_t)N * 4);
  int*   rs   = (int*)  walloc((size_t)(N + 1) * 4);
  float* pool = (float*)walloc((size_t)G * 129 * 4);
  float* gcnt = pool + (size_t)G * 128;

  const bool small = (N <= 65535);
  const int gblocks = (N + 127) / 128;
  const int half = (N + 1) >> 1;
  const int aggGrid = ((half + 3) / 4) * 8;

  transpose2_w_k<<<128, 256, 0, stream>>>(W1, W2, W1t, W2t);

  if (small) {
    const int B    = (N + 255) >> 8;
    const int nblk = (E + CHUNK - 1) / CHUNK;
    unsigned short* col = (unsigned short*)walloc((size_t)E * 2);
    unsigned int*   tmp = (unsigned int*)  walloc((size_t)E * 4);
    int* blk_cnt     = (int*)walloc((size_t)B * nblk * 4);
    int* bucket_tot  = (int*)walloc((size_t)B * 4);
    int* bucket_base = (int*)walloc((size_t)(B + 1) * 4);

    hist_k<<<nblk, 256, 0, stream>>>(dst, E, blk_cnt, nblk, B);
    bucket_prefix_k<<<(B + 3) / 4, 256, 0, stream>>>(blk_cnt, nblk, B, bucket_tot);
    bucket_base_k<<<1, 64, 0, stream>>>(bucket_tot, B, bucket_base);
    bucket_scatter_k<<<nblk, 256, 0, stream>>>(src, dst, E, blk_cnt, nblk, bucket_base, B, tmp);
    bucket_cntfill_k<<<B, 256, 0, stream>>>(tmp, bucket_base, N, E, dinv, rs, col);

    gemm_bf_k<true><<<gblocks, 256, 0, stream>>>(x, W1t, B2, N);
    aggc_k<unsigned short, false><<<aggGrid, 256, 0, stream>>>(B2, rs, col, dinv, b1, B3, N, half);
    gemm_bf_k<false><<<gblocks, 256, 0, stream>>>(B3, W2t, B2, N);
    aggc_k<unsigned short, true><<<aggGrid, 256, 0, stream>>>(B2, rs, col, dinv, b2, a2, N, half);
  } else {
    const int nb = (N + 1023) / 1024;
    int* cnt    = (int*)walloc((size_t)N * 4);
    int* cursor = (int*)walloc((size_t)N * 4);
    int* col    = (int*)walloc((size_t)E * 4);
    int* partials = (int*)walloc(256 * 4);
    hipMemsetAsync(cnt, 0, (size_t)N * 4, stream);
    count_edges_k<<<(E + 255) / 256, 256, 0, stream>>>(dst, E, cnt);
    scan1_k<<<nb, 1024, 0, stream>>>(cnt, rs, partials, N);
    scan2_k<<<1, 64, 0, stream>>>(partials, nb);
    scan3_k<<<(N + 255) / 256, 256, 0, stream>>>(rs, cursor, partials, N, E);
    dinv_k<<<(N + 255) / 256, 256, 0, stream>>>(cnt, dinv, N);
    fill_csr_k<int><<<(E + 255) / 256, 256, 0, stream>>>(src, dst, E, cursor, col);

    gemm_bf_k<true><<<gblocks, 256, 0, stream>>>(x, W1t, B2, N);
    aggc_k<int, false><<<aggGrid, 256, 0, stream>>>(B2, rs, col, dinv, b1, B3, N, half);
    gemm_bf_k<false><<<gblocks, 256, 0, stream>>>(B3, W2t, B2, N);
    aggc_k<int, true><<<aggGrid, 256, 0, stream>>>(B2, rs, col, dinv, b2, a2, N, half);
  }

  hipMemsetAsync(pool, 0, (size_t)G * 129 * 4, stream);
  pool_k<<<(N + 63) / 64, 128, 0, stream>>>(a2, bat, N, pool, gcnt);
  classify_k<<<G, 128, 0, stream>>>(pool, gcnt, Wc1, bc1, Wc2, bc2, out, NC);
}

// Round 8
// 314.408 us; speedup vs baseline: 1.3904x; 1.3904x over previous
//
#include <hip/hip_runtime.h>
#include <cstdint>
#include <cstddef>

#define CHUNK 4096

typedef __attribute__((ext_vector_type(8))) short short8;
typedef __attribute__((ext_vector_type(4))) float f32x4;

__device__ __forceinline__ float bf2f(unsigned short u) {
  return __uint_as_float(((unsigned)u) << 16);
}
__device__ __forceinline__ unsigned short f2bf(float f) {
  unsigned u = __float_as_uint(f);
  u += 0x7fffu + ((u >> 16) & 1u);   // RNE
  return (unsigned short)(u >> 16);
}

// both W1,W2 [128][128] fp32 -> Wt[n][k] bf16, single launch (grid 128)
__global__ void transpose2_w_k(const float* __restrict__ W1, const float* __restrict__ W2,
                               unsigned short* __restrict__ W1t, unsigned short* __restrict__ W2t) {
  int idx = blockIdx.x * 256 + threadIdx.x;
  const float* W = (idx < 16384) ? W1 : W2;
  unsigned short* Wt = (idx < 16384) ? W1t : W2t;
  int i = idx & 16383;
  int k = i >> 7, n = i & 127;
  Wt[n * 128 + k] = f2bf(W[i]);
}

// ---------------- fallback CSR build (N > 65535) ----------------
__global__ void count_edges_k(const int* __restrict__ dst, int E, int* __restrict__ cnt) {
  int e = blockIdx.x * blockDim.x + threadIdx.x;
  if (e < E) atomicAdd(&cnt[dst[e]], 1);
}

__global__ void dinv_k(const int* __restrict__ cnt, float* __restrict__ dinv, int n) {
  int i = blockIdx.x * blockDim.x + threadIdx.x;
  if (i < n) dinv[i] = rsqrtf((float)cnt[i] + 1.0f);
}

template <typename CT>
__global__ void fill_csr_k(const int* __restrict__ src, const int* __restrict__ dst, int E,
                           int* __restrict__ cursor, CT* __restrict__ col) {
  int e = blockIdx.x * blockDim.x + threadIdx.x;
  if (e < E) {
    int d = dst[e], s = src[e];
    int pos = atomicAdd(&cursor[d], 1);
    col[pos] = (CT)s;
  }
}

__global__ void scan1_k(const int* __restrict__ cnt, int* __restrict__ rs,
                        int* __restrict__ partials, int n) {
  __shared__ int s[1024];
  int t = threadIdx.x;
  int gid = blockIdx.x * 1024 + t;
  int v = (gid < n) ? cnt[gid] : 0;
  s[t] = v;
  __syncthreads();
  for (int off = 1; off < 1024; off <<= 1) {
    int u = (t >= off) ? s[t - off] : 0;
    __syncthreads();
    s[t] += u;
    __syncthreads();
  }
  if (gid < n) rs[gid] = s[t] - v;
  if (t == 1023) partials[blockIdx.x] = s[1023];
}

__global__ void scan2_k(int* __restrict__ partials, int nb) {
  if (threadIdx.x == 0 && blockIdx.x == 0) {
    int acc = 0;
    for (int i = 0; i < nb; i++) { int v = partials[i]; partials[i] = acc; acc += v; }
  }
}

__global__ void scan3_k(int* __restrict__ rs, int* __restrict__ cursor,
                        const int* __restrict__ partials, int n, int total) {
  int gid = blockIdx.x * blockDim.x + threadIdx.x;
  if (gid < n) {
    int v = rs[gid] + partials[gid >> 10];
    rs[gid] = v;
    cursor[gid] = v;
  }
  if (gid == 0) rs[n] = total;
}

// ---------------- single-pass bucket scatter (N <= 65535) ----------------
// bucket b = dst>>8; per-bucket arena tmp[b*cap .. ]; one global atomicAdd
// per (block,bucket) claims a contiguous run -> full-line writes.
__global__ __launch_bounds__(256) void scatter_atomic_k(const int* __restrict__ src,
                                                        const int* __restrict__ dst, int E,
                                                        int* __restrict__ gcur,
                                                        unsigned int* __restrict__ tmp,
                                                        int cap, int B) {
  __shared__ unsigned pk[CHUNK];
  __shared__ unsigned char bk[CHUNK];
  __shared__ int h[256];
  __shared__ int cur[256];
  __shared__ int base_s[256];
  int t = threadIdx.x;
  h[t] = 0;
  __syncthreads();
  int e0 = blockIdx.x * CHUNK;
  int e1 = e0 + CHUNK; if (e1 > E) e1 = E;
  int m = e1 - e0;
  for (int i = t; i < m; i += 256) {
    int d = dst[e0 + i], s = src[e0 + i];
    int b = d >> 8;
    pk[i] = ((unsigned)s << 8) | (unsigned)(d & 255);
    bk[i] = (unsigned char)b;
    atomicAdd(&h[b], 1);
  }
  __syncthreads();
  if (t < B && h[t] > 0) base_s[t] = atomicAdd(&gcur[t], h[t]);
  cur[t] = 0;
  __syncthreads();
  for (int i = t; i < m; i += 256) {
    int b = bk[i];
    int r = atomicAdd(&cur[b], 1);
    int p = base_s[b] + r;
    if (p < cap) tmp[(size_t)b * cap + p] = pk[i];
  }
}

// exclusive prefix over bucket counts (single wave)
__global__ void base2_k(const int* __restrict__ gcur, int B, int cap,
                        int* __restrict__ bucket_base) {
  int lane = threadIdx.x;
  int running = 0;
  for (int c0 = 0; c0 < B; c0 += 64) {
    int idx = c0 + lane;
    int cb = (idx < B) ? gcur[idx] : 0;
    if (cb > cap) cb = cap;
    int v = cb;
    #pragma unroll
    for (int off = 1; off < 64; off <<= 1) {
      int u = __shfl_up(v, off);
      if (lane >= off) v += u;
    }
    int tot = __shfl(v, 63);
    if (idx < B) bucket_base[idx] = running + (v - cb);
    running += tot;
  }
  if (lane == 0) bucket_base[B] = running;
}

// fused per-bucket: degree count + LDS scan -> rs/dinv + CSR fill
__global__ __launch_bounds__(256) void cntfill2_k(const unsigned int* __restrict__ tmp,
                                                  const int* __restrict__ gcur,
                                                  const int* __restrict__ bucket_base,
                                                  int N, int E, int cap,
                                                  float* __restrict__ dinv,
                                                  int* __restrict__ rs,
                                                  unsigned short* __restrict__ col) {
  __shared__ int c[256];
  __shared__ int cur[256];
  int b = blockIdx.x, t = threadIdx.x;
  c[t] = 0;
  __syncthreads();
  int cnt_b = gcur[b]; if (cnt_b > cap) cnt_b = cap;
  const unsigned* tb = tmp + (size_t)b * cap;
  for (int i = t; i < cnt_b; i += 256) atomicAdd(&c[tb[i] & 255u], 1);
  __syncthreads();
  int v = c[t];
  cur[t] = v;
  __syncthreads();
  for (int off = 1; off < 256; off <<= 1) {
    int u = (t >= off) ? cur[t - off] : 0;
    __syncthreads();
    cur[t] += u;
    __syncthreads();
  }
  int rsv = bucket_base[b] + cur[t] - v;
  int node = (b << 8) + t;
  if (node < N) {
    rs[node] = rsv;
    dinv[node] = rsqrtf((float)v + 1.0f);
  }
  if (b == 0 && t == 0) rs[N] = E;
  __syncthreads();
  cur[t] = rsv;
  __syncthreads();
  for (int i = t; i < cnt_b; i += 256) {
    unsigned u = tb[i];
    int pos = atomicAdd(&cur[u & 255u], 1);
    col[pos] = (unsigned short)(u >> 8);
  }
}

// ---------------- MFMA GEMM: C[N,128](bf16 row-major) = A[N,128] @ W ----------------
template <bool AF32>
__global__ __launch_bounds__(256) void gemm_bf_k(const void* __restrict__ Ap,
                                                 const unsigned short* __restrict__ Wt,
                                                 unsigned short* __restrict__ C, int N) {
  __shared__ unsigned short Ws[128 * 136];   // 34.8KB; reused as Cs (128*132=33.8KB)
  for (int idx = threadIdx.x; idx < 2048; idx += 256) {
    int n = idx >> 4, c = idx & 15;
    *(uint4*)&Ws[n * 136 + c * 8] = ((const uint4*)Wt)[idx];
  }
  __syncthreads();
  const int w = threadIdx.x >> 6;
  const int lane = threadIdx.x & 63;
  const int quad = lane >> 4, l16 = lane & 15;
  const int rb = blockIdx.x * 128 + w * 32;
  f32x4 acc[2][8] = {};
  #pragma unroll
  for (int ks = 0; ks < 4; ks++) {
    short8 aF[2];
    #pragma unroll
    for (int m = 0; m < 2; m++) {
      int r = rb + m * 16 + l16;
      short8 a = {};
      if (r < N) {
        if (AF32) {
          const float* ar = (const float*)Ap + (size_t)r * 128 + ks * 32 + quad * 8;
          float4 u0 = *(const float4*)ar;
          float4 u1 = *(const float4*)(ar + 4);
          a[0] = (short)f2bf(u0.x); a[1] = (short)f2bf(u0.y);
          a[2] = (short)f2bf(u0.z); a[3] = (short)f2bf(u0.w);
          a[4] = (short)f2bf(u1.x); a[5] = (short)f2bf(u1.y);
          a[6] = (short)f2bf(u1.z); a[7] = (short)f2bf(u1.w);
        } else {
          a = *(const short8*)((const unsigned short*)Ap + (size_t)r * 128 + ks * 32 + quad * 8);
        }
      }
      aF[m] = a;
    }
    #pragma unroll
    for (int t = 0; t < 8; t++) {
      short8 bF = *(const short8*)&Ws[(t * 16 + l16) * 136 + ks * 32 + quad * 8];
      acc[0][t] = __builtin_amdgcn_mfma_f32_16x16x32_bf16(aF[0], bF, acc[0][t], 0, 0, 0);
      acc[1][t] = __builtin_amdgcn_mfma_f32_16x16x32_bf16(aF[1], bF, acc[1][t], 0, 0, 0);
    }
  }
  __syncthreads();
  unsigned short* Cs = Ws;
  #pragma unroll
  for (int m = 0; m < 2; m++) {
    int rloc = w * 32 + m * 16 + quad * 4;
    #pragma unroll
    for (int t = 0; t < 8; t++)
      #pragma unroll
      for (int rg = 0; rg < 4; rg++)
        Cs[(rloc + rg) * 132 + t * 16 + l16] = f2bf(acc[m][t][rg]);
  }
  __syncthreads();
  const int r0 = blockIdx.x * 128;
  for (int idx = threadIdx.x; idx < 2048; idx += 256) {
    int row = idx >> 4, c = idx & 15;
    int rr = r0 + row;
    if (rr < N) {
      uint2 a = *(uint2*)&Cs[row * 132 + c * 8];
      uint2 b = *(uint2*)&Cs[row * 132 + c * 8 + 4];
      ((uint4*)C)[(size_t)rr * 16 + c] = make_uint4(a.x, a.y, b.x, b.y);
    }
  }
}

// ---------------- aggregation: 16 lanes/edge, 8 edges in flight (row-major) ----------------
template <typename CT>
__global__ __launch_bounds__(256) void agg8_k(const unsigned short* __restrict__ h,
                                              const int* __restrict__ rs,
                                              const CT* __restrict__ col,
                                              const float* __restrict__ dinv,
                                              const float* __restrict__ bias,
                                              unsigned short* __restrict__ outp, int n) {
  int wid = (blockIdx.x * blockDim.x + threadIdx.x) >> 6;
  int lane = threadIdx.x & 63;
  if (wid >= n) return;
  const int g = lane >> 4;
  const int l = lane & 15;
  float di = dinv[wid];
  float acc[8];
  {
    uint4 sv = ((const uint4*)(h + (size_t)wid * 128))[l];
    float ws = (g == 0) ? di : 0.f;
    acc[0] = bf2f((unsigned short)sv.x) * ws;
    acc[1] = bf2f((unsigned short)(sv.x >> 16)) * ws;
    acc[2] = bf2f((unsigned short)sv.y) * ws;
    acc[3] = bf2f((unsigned short)(sv.y >> 16)) * ws;
    acc[4] = bf2f((unsigned short)sv.z) * ws;
    acc[5] = bf2f((unsigned short)(sv.z >> 16)) * ws;
    acc[6] = bf2f((unsigned short)sv.w) * ws;
    acc[7] = bf2f((unsigned short)(sv.w >> 16)) * ws;
  }
  int beg = rs[wid], end = rs[wid + 1];
  for (int base = beg; base < end; base += 8) {
    int e0 = base + g, e1 = base + 4 + g;
    int i0 = (e0 < end) ? e0 : end - 1;
    int i1 = (e1 < end) ? e1 : end - 1;
    int s0 = (int)col[i0], s1 = (int)col[i1];
    float w0 = (e0 < end) ? dinv[s0] : 0.f;
    float w1 = (e1 < end) ? dinv[s1] : 0.f;
    uint4 h0 = ((const uint4*)(h + (size_t)s0 * 128))[l];
    uint4 h1 = ((const uint4*)(h + (size_t)s1 * 128))[l];
    acc[0] += bf2f((unsigned short)h0.x) * w0 + bf2f((unsigned short)h1.x) * w1;
    acc[1] += bf2f((unsigned short)(h0.x >> 16)) * w0 + bf2f((unsigned short)(h1.x >> 16)) * w1;
    acc[2] += bf2f((unsigned short)h0.y) * w0 + bf2f((unsigned short)h1.y) * w1;
    acc[3] += bf2f((unsigned short)(h0.y >> 16)) * w0 + bf2f((unsigned short)(h1.y >> 16)) * w1;
    acc[4] += bf2f((unsigned short)h0.z) * w0 + bf2f((unsigned short)h1.z) * w1;
    acc[5] += bf2f((unsigned short)(h0.z >> 16)) * w0 + bf2f((unsigned short)(h1.z >> 16)) * w1;
    acc[6] += bf2f((unsigned short)h0.w) * w0 + bf2f((unsigned short)h1.w) * w1;
    acc[7] += bf2f((unsigned short)(h0.w >> 16)) * w0 + bf2f((unsigned short)(h1.w >> 16)) * w1;
  }
  #pragma unroll
  for (int j = 0; j < 8; j++) {
    acc[j] += __shfl_xor(acc[j], 16);
    acc[j] += __shfl_xor(acc[j], 32);
  }
  if (g == 0) {
    float4 bA = *(const float4*)(bias + l * 8);
    float4 bB = *(const float4*)(bias + l * 8 + 4);
    float r0 = fmaxf(acc[0] * di + bA.x, 0.f);
    float r1 = fmaxf(acc[1] * di + bA.y, 0.f);
    float r2 = fmaxf(acc[2] * di + bA.z, 0.f);
    float r3 = fmaxf(acc[3] * di + bA.w, 0.f);
    float r4 = fmaxf(acc[4] * di + bB.x, 0.f);
    float r5 = fmaxf(acc[5] * di + bB.y, 0.f);
    float r6 = fmaxf(acc[6] * di + bB.z, 0.f);
    float r7 = fmaxf(acc[7] * di + bB.w, 0.f);
    uint4 v;
    v.x = (unsigned)f2bf(r0) | ((unsigned)f2bf(r1) << 16);
    v.y = (unsigned)f2bf(r2) | ((unsigned)f2bf(r3) << 16);
    v.z = (unsigned)f2bf(r4) | ((unsigned)f2bf(r5) << 16);
    v.w = (unsigned)f2bf(r6) | ((unsigned)f2bf(r7) << 16);
    ((uint4*)outp)[(size_t)wid * 16 + l] = v;
  }
}

// ---------------- per-graph mean pool (bf16 input) ----------------
__global__ void poolb_k(const unsigned short* __restrict__ h, const int* __restrict__ batch, int n,
                        float* __restrict__ pool, float* __restrict__ gcnt) {
  int f = threadIdx.x;
  int n0 = blockIdx.x * 64;
  if (n0 >= n) return;
  int n1 = n0 + 64; if (n1 > n) n1 = n;
  int gcur = batch[n0];
  float acc = 0.f, cacc = 0.f;
  for (int i = n0; i < n1; i++) {
    int g = batch[i];
    if (g != gcur) {
      atomicAdd(&pool[gcur * 128 + f], acc);
      if (f == 0) atomicAdd(&gcnt[gcur], cacc);
      acc = 0.f; cacc = 0.f; gcur = g;
    }
    acc += bf2f(h[(size_t)i * 128 + f]);
    cacc += 1.f;
  }
  atomicAdd(&pool[gcur * 128 + f], acc);
  if (f == 0) atomicAdd(&gcnt[gcur], cacc);
}

// ---------------- classifier head ----------------
__global__ void classify_k(const float* __restrict__ pool, const float* __restrict__ gcnt,
                           const float* __restrict__ Wc1, const float* __restrict__ bc1,
                           const float* __restrict__ Wc2, const float* __restrict__ bc2,
                           float* __restrict__ out, int nc) {
  __shared__ float gs[128];
  __shared__ float zs[128];
  int g = blockIdx.x, t = threadIdx.x;
  float c = gcnt[g]; if (c < 1.f) c = 1.f;
  gs[t] = pool[g * 128 + t] / c;
  __syncthreads();
  float acc = bc1[t];
  for (int k = 0; k < 128; k++) acc += gs[k] * Wc1[k * 128 + t];
  zs[t] = fmaxf(acc, 0.f);
  __syncthreads();
  if (t < nc) {
    float o = bc2[t];
    for (int k = 0; k < 128; k++) o += zs[k] * Wc2[k * nc + t];
    out[g * nc + t] = o;
  }
}

extern "C" void kernel_launch(void* const* d_in, const int* in_sizes, int n_in,
                              void* d_out, int out_size, void* d_ws, size_t ws_size,
                              hipStream_t stream) {
  const float* x   = (const float*)d_in[0];
  const int*   ei  = (const int*)d_in[1];
  const int*   bat = (const int*)d_in[2];
  const float* W1  = (const float*)d_in[3];
  const float* b1  = (const float*)d_in[4];
  const float* W2  = (const float*)d_in[5];
  const float* b2  = (const float*)d_in[6];
  const float* Wc1 = (const float*)d_in[7];
  const float* bc1 = (const float*)d_in[8];
  const float* Wc2 = (const float*)d_in[9];
  const float* bc2 = (const float*)d_in[10];
  float* out = (float*)d_out;

  const int N  = in_sizes[0] / 128;
  const int E  = in_sizes[1] / 2;
  const int NC = in_sizes[10];
  const int G  = out_size / NC;
  const int* src = ei;
  const int* dst = ei + E;
  (void)n_in; (void)ws_size;

  size_t off = 0;
  auto walloc = [&](size_t bytes) -> void* {
    void* p = (char*)d_ws + off;
    off += (bytes + 255) & ~(size_t)255;
    return p;
  };
  unsigned short* B2 = (unsigned short*)walloc((size_t)N * 128 * 2);
  unsigned short* B3 = (unsigned short*)walloc((size_t)N * 128 * 2);
  unsigned short* W1t = (unsigned short*)walloc(128 * 128 * 2);
  unsigned short* W2t = (unsigned short*)walloc(128 * 128 * 2);
  float* dinv = (float*)walloc((size_t)N * 4);
  int*   rs   = (int*)  walloc((size_t)(N + 1) * 4);
  float* pool = (float*)walloc((size_t)G * 129 * 4);
  float* gcnt = pool + (size_t)G * 128;

  const bool small = (N <= 65535);
  const int gblocks = (N + 127) / 128;
  const int aggGrid = (N + 3) / 4;   // 1 wave/node, 4 waves/block

  transpose2_w_k<<<128, 256, 0, stream>>>(W1, W2, W1t, W2t);

  if (small) {
    const int B    = (N + 255) >> 8;
    const int nblk = (E + CHUNK - 1) / CHUNK;
    const int cap  = (E + B - 1) / B + 2048;   // +23 sigma for uniform dst: no overflow
    unsigned short* col = (unsigned short*)walloc((size_t)E * 2);
    unsigned int*   tmp = (unsigned int*)  walloc((size_t)B * cap * 4);
    int* gcur        = (int*)walloc((size_t)B * 4);
    int* bucket_base = (int*)walloc((size_t)(B + 1) * 4);

    hipMemsetAsync(gcur, 0, (size_t)B * 4, stream);
    scatter_atomic_k<<<nblk, 256, 0, stream>>>(src, dst, E, gcur, tmp, cap, B);
    base2_k<<<1, 64, 0, stream>>>(gcur, B, cap, bucket_base);
    cntfill2_k<<<B, 256, 0, stream>>>(tmp, gcur, bucket_base, N, E, cap, dinv, rs, col);

    gemm_bf_k<true><<<gblocks, 256, 0, stream>>>(x, W1t, B2, N);
    agg8_k<unsigned short><<<aggGrid, 256, 0, stream>>>(B2, rs, col, dinv, b1, B3, N);
    gemm_bf_k<false><<<gblocks, 256, 0, stream>>>(B3, W2t, B2, N);
    agg8_k<unsigned short><<<aggGrid, 256, 0, stream>>>(B2, rs, col, dinv, b2, B3, N);
  } else {
    const int nb = (N + 1023) / 1024;
    int* cnt    = (int*)walloc((size_t)N * 4);
    int* cursor = (int*)walloc((size_t)N * 4);
    int* col    = (int*)walloc((size_t)E * 4);
    int* partials = (int*)walloc(256 * 4);
    hipMemsetAsync(cnt, 0, (size_t)N * 4, stream);
    count_edges_k<<<(E + 255) / 256, 256, 0, stream>>>(dst, E, cnt);
    scan1_k<<<nb, 1024, 0, stream>>>(cnt, rs, partials, N);
    scan2_k<<<1, 64, 0, stream>>>(partials, nb);
    scan3_k<<<(N + 255) / 256, 256, 0, stream>>>(rs, cursor, partials, N, E);
    dinv_k<<<(N + 255) / 256, 256, 0, stream>>>(cnt, dinv, N);
    fill_csr_k<int><<<(E + 255) / 256, 256, 0, stream>>>(src, dst, E, cursor, col);

    gemm_bf_k<true><<<gblocks, 256, 0, stream>>>(x, W1t, B2, N);
    agg8_k<int><<<aggGrid, 256, 0, stream>>>(B2, rs, col, dinv, b1, B3, N);
    gemm_bf_k<false><<<gblocks, 256, 0, stream>>>(B3, W2t, B2, N);
    agg8_k<int><<<aggGrid, 256, 0, stream>>>(B2, rs, col, dinv, b2, B3, N);
  }

  hipMemsetAsync(pool, 0, (size_t)G * 129 * 4, stream);
  poolb_k<<<(N + 63) / 64, 128, 0, stream>>>(B3, bat, N, pool, gcnt);
  classify_k<<<G, 128, 0, stream>>>(pool, gcnt, Wc1, bc1, Wc2, bc2, out, NC);
}